// Round 4
// baseline (402.353 us; speedup 1.0000x reference)
//
#include <hip/hip_runtime.h>

#define T_TOK 16384
#define IN_F  1024
#define OUT_F 4096
#define NH    32

// ---------------------------------------------------------------------------
// K1: w_t[h][o] = amp[o][h] * cosf(phase[o][h])   (transposed, into workspace)
// ---------------------------------------------------------------------------
__global__ __launch_bounds__(256) void wreal_kernel(
    const float* __restrict__ phase, const float* __restrict__ amp,
    float* __restrict__ w_t)
{
    int idx = blockIdx.x * 256 + threadIdx.x;   // 0 .. 131071
    int o = idx & (OUT_F - 1);
    int h = idx >> 12;                          // idx / 4096
    float p = phase[o * NH + h];
    float a = amp[o * NH + h];
    w_t[h * OUT_F + o] = a * cosf(p);
}

// ---------------------------------------------------------------------------
// Fused K2+K3: one block = 64 tokens end-to-end.
// Phase A (== K2-old verbatim): res[32][64] tile via K-chunks of 128 staged in
// LDS; acc[4 tok][2 h] per thread; result parked in rs[32][68] (8.7 KB LDS).
// Phase B (== K3-old verbatim math): 32 o-chunks of 128; w-tile double-buffered
// in LDS with issue-early/write-late staging (T14); thread = 4 tok x 8 out.
// Eliminates res_t global write+read and one kernel launch. Summation order
// identical to the unfused R0 kernels -> bitwise-same absmax expected.
// LDS: rs 8.7 KB + sbuf 49.5 KB (phase A xs+bs, reused as 2x16.9 KB wl dbuf).
// ---------------------------------------------------------------------------
#define F_TT  64
#define KC    128
#define XS_S  132
#define RS_S  68
#define WT_S  132
#define NOC   (OUT_F / 128)   // 32 o-chunks

__global__ __launch_bounds__(256) void fused_kernel(
    const float* __restrict__ x,      // [16384][1024]
    const float* __restrict__ basis,  // [32][1024]
    const float* __restrict__ w_t,    // [32][4096]
    float* __restrict__ out)          // [16384][4096]
{
    __shared__ float rs[NH * RS_S];                      // 8.7 KB, whole kernel
    __shared__ float sbuf[F_TT * XS_S + NH * XS_S];      // 49.5 KB, phase-shared

    const int tid = threadIdx.x;
    const int t0  = blockIdx.x * F_TT;
    const int ty  = tid >> 4;   // 0..15 : token group (4 tokens)
    const int tx  = tid & 15;

    // ---------------- phase A: resonance tile ----------------
    float* xs = sbuf;                 // [64][132]
    float* bs = sbuf + F_TT * XS_S;   // [32][132]

    float acc[4][2] = {};
    for (int i0 = 0; i0 < IN_F; i0 += KC) {
        #pragma unroll
        for (int it = 0; it < 8; ++it) {
            int lin = it * 256 + tid;
            int r = lin >> 5, c = lin & 31;           // 32 float4 per row
            float4 v = *(const float4*)(x + (size_t)(t0 + r) * IN_F + i0 + 4 * c);
            *(float4*)(xs + r * XS_S + 4 * c) = v;
        }
        #pragma unroll
        for (int it = 0; it < 4; ++it) {
            int lin = it * 256 + tid;
            int r = lin >> 5, c = lin & 31;
            float4 v = *(const float4*)(basis + (size_t)r * IN_F + i0 + 4 * c);
            *(float4*)(bs + r * XS_S + 4 * c) = v;
        }
        __syncthreads();

        #pragma unroll 4
        for (int i = 0; i < KC; i += 4) {
            float4 xa[4], bb[2];
            #pragma unroll
            for (int k = 0; k < 4; ++k)
                xa[k] = *(const float4*)(xs + (4 * ty + k) * XS_S + i);
            #pragma unroll
            for (int j = 0; j < 2; ++j)
                bb[j] = *(const float4*)(bs + (tx + 16 * j) * XS_S + i);
            #pragma unroll
            for (int k = 0; k < 4; ++k) {
                #pragma unroll
                for (int j = 0; j < 2; ++j) {
                    acc[k][j] += xa[k].x * bb[j].x;
                    acc[k][j] += xa[k].y * bb[j].y;
                    acc[k][j] += xa[k].z * bb[j].z;
                    acc[k][j] += xa[k].w * bb[j].w;
                }
            }
        }
        __syncthreads();
    }

    // park res tile in LDS: rs[h][t_local], t_local = 4*ty+k
    #pragma unroll
    for (int j = 0; j < 2; ++j)
        *(float4*)(rs + (tx + 16 * j) * RS_S + 4 * ty) =
            make_float4(acc[0][j], acc[1][j], acc[2][j], acc[3][j]);

    // ---------------- phase B: output tiles ----------------
    float* wl = sbuf;                 // [2][32][132] dbuf (8448 floats, fits)
    float4 nw[4];

    // stage oc=0 into wl[0]  (sbuf reads all done: barrier after last chunk)
    #pragma unroll
    for (int it = 0; it < 4; ++it) {
        int lin = it * 256 + tid;
        int r = lin >> 5, c = lin & 31;
        nw[it] = *(const float4*)(w_t + (size_t)r * OUT_F + 4 * c);
    }
    #pragma unroll
    for (int it = 0; it < 4; ++it) {
        int lin = it * 256 + tid;
        int r = lin >> 5, c = lin & 31;
        *(float4*)(wl + r * WT_S + 4 * c) = nw[it];
    }
    // prefetch oc=1 into regs
    #pragma unroll
    for (int it = 0; it < 4; ++it) {
        int lin = it * 256 + tid;
        int r = lin >> 5, c = lin & 31;
        nw[it] = *(const float4*)(w_t + (size_t)r * OUT_F + 128 + 4 * c);
    }
    __syncthreads();   // rs + wl[0] visible to all

    for (int oc = 0; oc < NOC; ++oc) {
        const float* wcur = wl + (oc & 1) * (NH * WT_S);
        const int o0 = oc * 128;

        float acc2[4][8] = {};
        #pragma unroll
        for (int h = 0; h < NH; ++h) {
            float4 rt = *(const float4*)(rs + h * RS_S + 4 * ty);
            float4 wa = *(const float4*)(wcur + h * WT_S + 4 * tx);
            float4 wb = *(const float4*)(wcur + h * WT_S + 64 + 4 * tx);
            float r4[4] = {rt.x, rt.y, rt.z, rt.w};
            float w8[8] = {wa.x, wa.y, wa.z, wa.w, wb.x, wb.y, wb.z, wb.w};
            #pragma unroll
            for (int k = 0; k < 4; ++k)
                #pragma unroll
                for (int j = 0; j < 8; ++j)
                    acc2[k][j] += r4[k] * w8[j];
        }

        #pragma unroll
        for (int k = 0; k < 4; ++k) {
            float* po = out + (size_t)(t0 + 4 * ty + k) * OUT_F + o0;
            *(float4*)(po + 4 * tx)      = make_float4(acc2[k][0], acc2[k][1], acc2[k][2], acc2[k][3]);
            *(float4*)(po + 64 + 4 * tx) = make_float4(acc2[k][4], acc2[k][5], acc2[k][6], acc2[k][7]);
        }

        if (oc + 1 < NOC) {
            // write prefetched tile into the OTHER buffer (nobody reads it now;
            // slow waves still reading wcur are untouched; barrier below
            // publishes before anyone reads it in iter oc+1)
            float* wnext = wl + ((oc + 1) & 1) * (NH * WT_S);
            #pragma unroll
            for (int it = 0; it < 4; ++it) {
                int lin = it * 256 + tid;
                int r = lin >> 5, c = lin & 31;
                *(float4*)(wnext + r * WT_S + 4 * c) = nw[it];
            }
            if (oc + 2 < NOC) {
                #pragma unroll
                for (int it = 0; it < 4; ++it) {
                    int lin = it * 256 + tid;
                    int r = lin >> 5, c = lin & 31;
                    nw[it] = *(const float4*)(w_t + (size_t)r * OUT_F + (oc + 2) * 128 + 4 * c);
                }
            }
            __syncthreads();
        }
    }
}

// ---------------------------------------------------------------------------
extern "C" void kernel_launch(void* const* d_in, const int* in_sizes, int n_in,
                              void* d_out, int out_size, void* d_ws, size_t ws_size,
                              hipStream_t stream)
{
    const float* x     = (const float*)d_in[0];  // [16384,1024]
    const float* basis = (const float*)d_in[1];  // [32,1024]
    const float* phase = (const float*)d_in[2];  // [4096,32]
    const float* amp   = (const float*)d_in[3];  // [4096,32]
    float* out = (float*)d_out;                  // [16384,4096] fp32

    float* w_t = (float*)d_ws;                   // 32*4096 floats = 512 KB

    wreal_kernel<<<dim3((OUT_F * NH) / 256), dim3(256), 0, stream>>>(phase, amp, w_t);
    fused_kernel<<<dim3(T_TOK / F_TT), dim3(256), 0, stream>>>(x, basis, w_t, out);
}

// Round 5
// 343.988 us; speedup vs baseline: 1.1697x; 1.1697x over previous
//
#include <hip/hip_runtime.h>

#define T_TOK 16384
#define IN_F  1024
#define OUT_F 4096
#define NH    32

// ---------------------------------------------------------------------------
// K1: w_t[h][o] = amp[o][h] * cosf(phase[o][h])   (transposed, into workspace)
// ---------------------------------------------------------------------------
__global__ __launch_bounds__(256) void wreal_kernel(
    const float* __restrict__ phase, const float* __restrict__ amp,
    float* __restrict__ w_t)
{
    int idx = blockIdx.x * 256 + threadIdx.x;   // 0 .. 131071
    int o = idx & (OUT_F - 1);
    int h = idx >> 12;                          // idx / 4096
    float p = phase[o * NH + h];
    float a = amp[o * NH + h];
    w_t[h * OUT_F + o] = a * cosf(p);
}

// ---------------------------------------------------------------------------
// K2: res_p[s][h][t] = sum_{i in K-quarter s} x[t][i] * basis[h][i]
// R0 inner structure VERBATIM (6 ds_read_b128 per 32 fmac, 4 tok x 2 h), but
// K split 4-way across blockIdx.y: grid 256x4 = 1024 blocks = 4096 waves ->
// 3 waves/SIMD (LDS 50.7KB -> 3 blocks/CU), vs R0's 1 wave/SIMD (the theory:
// that starvation made K2 ~100us with all LDS/global latency exposed).
// Chip-wide staging/fmac instruction totals identical to R0.
// ---------------------------------------------------------------------------
#define G1_TT 64
#define G1_KC 128
#define G1_S  132
#define KSPL  4
#define KQ    (IN_F / KSPL)   // 256

__global__ __launch_bounds__(256) void resonance_kernel(
    const float* __restrict__ x,      // [16384][1024]
    const float* __restrict__ basis,  // [32][1024]
    float* __restrict__ res_p)        // [4][32][16384]
{
    __shared__ float xs[G1_TT * G1_S];   // 33.8 KB
    __shared__ float bs[NH * G1_S];      // 16.9 KB

    const int tid = threadIdx.x;
    const int t0  = blockIdx.x * G1_TT;
    const int ks  = blockIdx.y;              // K-quarter 0..3
    const int kb  = ks * KQ;
    const int ty  = tid >> 4;   // 0..15 : token group (4 tokens)
    const int tx  = tid & 15;   // h = tx, tx+16

    float acc[4][2] = {};

    for (int i0 = kb; i0 < kb + KQ; i0 += G1_KC) {
        // stage x tile: 64 rows x 128 floats = 2048 float4 / 256 thr = 8 each
        #pragma unroll
        for (int it = 0; it < 8; ++it) {
            int lin = it * 256 + tid;
            int r = lin >> 5, c = lin & 31;           // 32 float4 per row
            float4 v = *(const float4*)(x + (size_t)(t0 + r) * IN_F + i0 + 4 * c);
            *(float4*)(xs + r * G1_S + 4 * c) = v;
        }
        // stage basis tile: 32 x 128 = 1024 float4 / 256 thr = 4 each
        #pragma unroll
        for (int it = 0; it < 4; ++it) {
            int lin = it * 256 + tid;
            int r = lin >> 5, c = lin & 31;
            float4 v = *(const float4*)(basis + (size_t)r * IN_F + i0 + 4 * c);
            *(float4*)(bs + r * G1_S + 4 * c) = v;
        }
        __syncthreads();

        #pragma unroll 4
        for (int i = 0; i < G1_KC; i += 4) {
            float4 xa[4], bb[2];
            #pragma unroll
            for (int k = 0; k < 4; ++k)
                xa[k] = *(const float4*)(xs + (4 * ty + k) * G1_S + i);
            #pragma unroll
            for (int j = 0; j < 2; ++j)
                bb[j] = *(const float4*)(bs + (tx + 16 * j) * G1_S + i);
            #pragma unroll
            for (int k = 0; k < 4; ++k) {
                #pragma unroll
                for (int j = 0; j < 2; ++j) {
                    acc[k][j] += xa[k].x * bb[j].x;
                    acc[k][j] += xa[k].y * bb[j].y;
                    acc[k][j] += xa[k].z * bb[j].z;
                    acc[k][j] += xa[k].w * bb[j].w;
                }
            }
        }
        __syncthreads();
    }

    #pragma unroll
    for (int k = 0; k < 4; ++k)
        #pragma unroll
        for (int j = 0; j < 2; ++j)
            res_p[(size_t)(ks * NH + tx + 16 * j) * T_TOK + t0 + 4 * ty + k] = acc[k][j];
}

// ---------------------------------------------------------------------------
// K3: out[t][o] = sum_h (sum_s res_p[s][h][t]) * w_t[h][o]
// R0-VERBATIM structure (64 tok x 128 out tile, thread = 4 tok x 8 out), plus
// the 4-partial sum folded into rs staging (+3 f4 loads, +3 f4 adds / elem).
// ---------------------------------------------------------------------------
#define G2_TT 64
#define G2_OT 128
#define RS_S  68
#define WT_S  132

__global__ __launch_bounds__(256) void holo_out_kernel(
    const float* __restrict__ res_p,  // [4][32][16384]
    const float* __restrict__ w_t,    // [32][4096]
    float* __restrict__ out)          // [16384][4096]
{
    __shared__ float rs[NH * RS_S];   // 8.7 KB
    __shared__ float wl[NH * WT_S];   // 16.9 KB

    const int tid = threadIdx.x;
    const int o0  = blockIdx.x * G2_OT;
    const int t0  = blockIdx.y * G2_TT;
    const int ty  = tid >> 4;   // 0..15 : token group (4 tokens)
    const int tx  = tid & 15;   // output cols 4*tx and 64+4*tx

    // stage res tile: 32 rows x 64 floats = 512 float4 -> 2/thread,
    // summing the 4 K-partials on the way in.
    #pragma unroll
    for (int it = 0; it < 2; ++it) {
        int lin = it * 256 + tid;                 // 0..511
        int r = lin >> 4, c = lin & 15;           // 16 float4 per row
        const float* rp = res_p + (size_t)r * T_TOK + t0 + 4 * c;
        float4 v = *(const float4*)(rp);
        #pragma unroll
        for (int s = 1; s < KSPL; ++s) {
            float4 u = *(const float4*)(rp + (size_t)s * NH * T_TOK);
            v.x += u.x; v.y += u.y; v.z += u.z; v.w += u.w;
        }
        *(float4*)(rs + r * RS_S + 4 * c) = v;
    }
    // stage w_t tile: 32 rows x 128 floats = 1024 float4 -> 4/thread
    #pragma unroll
    for (int it = 0; it < 4; ++it) {
        int lin = it * 256 + tid;
        int r = lin >> 5, c = lin & 31;
        float4 v = *(const float4*)(w_t + (size_t)r * OUT_F + o0 + 4 * c);
        *(float4*)(wl + r * WT_S + 4 * c) = v;
    }
    __syncthreads();

    float acc[4][8] = {};
    #pragma unroll
    for (int h = 0; h < NH; ++h) {
        float4 rt = *(const float4*)(rs + h * RS_S + 4 * ty);
        float4 wa = *(const float4*)(wl + h * WT_S + 4 * tx);
        float4 wb = *(const float4*)(wl + h * WT_S + 64 + 4 * tx);
        float r4[4] = {rt.x, rt.y, rt.z, rt.w};
        float w8[8] = {wa.x, wa.y, wa.z, wa.w, wb.x, wb.y, wb.z, wb.w};
        #pragma unroll
        for (int k = 0; k < 4; ++k)
            #pragma unroll
            for (int j = 0; j < 8; ++j)
                acc[k][j] += r4[k] * w8[j];
    }

    #pragma unroll
    for (int k = 0; k < 4; ++k) {
        float* po = out + (size_t)(t0 + 4 * ty + k) * OUT_F + o0;
        *(float4*)(po + 4 * tx)      = make_float4(acc[k][0], acc[k][1], acc[k][2], acc[k][3]);
        *(float4*)(po + 64 + 4 * tx) = make_float4(acc[k][4], acc[k][5], acc[k][6], acc[k][7]);
    }
}

// ---------------------------------------------------------------------------
extern "C" void kernel_launch(void* const* d_in, const int* in_sizes, int n_in,
                              void* d_out, int out_size, void* d_ws, size_t ws_size,
                              hipStream_t stream)
{
    const float* x     = (const float*)d_in[0];  // [16384,1024]
    const float* basis = (const float*)d_in[1];  // [32,1024]
    const float* phase = (const float*)d_in[2];  // [4096,32]
    const float* amp   = (const float*)d_in[3];  // [4096,32]
    float* out = (float*)d_out;                  // [16384,4096] fp32

    float* res_p = (float*)d_ws;                        // 4*32*16384 floats = 8 MB
    float* w_t   = res_p + (size_t)KSPL * NH * T_TOK;   // 32*4096 floats = 512 KB

    wreal_kernel<<<dim3((OUT_F * NH) / 256), dim3(256), 0, stream>>>(phase, amp, w_t);
    resonance_kernel<<<dim3(T_TOK / G1_TT, KSPL), dim3(256), 0, stream>>>(x, basis, res_p);
    holo_out_kernel<<<dim3(OUT_F / G2_OT, T_TOK / G2_TT), dim3(256), 0, stream>>>(res_p, w_t, out);
}

// Round 6
// 343.937 us; speedup vs baseline: 1.1698x; 1.0001x over previous
//
#include <hip/hip_runtime.h>

#define T_TOK 16384
#define IN_F  1024
#define OUT_F 4096
#define NH    32

// ---------------------------------------------------------------------------
// K1: w_t[h][o] = amp[o][h] * cosf(phase[o][h])   (transposed, into workspace)
// ---------------------------------------------------------------------------
__global__ __launch_bounds__(256) void wreal_kernel(
    const float* __restrict__ phase, const float* __restrict__ amp,
    float* __restrict__ w_t)
{
    int idx = blockIdx.x * 256 + threadIdx.x;   // 0 .. 131071
    int o = idx & (OUT_F - 1);
    int h = idx >> 12;                          // idx / 4096
    float p = phase[o * NH + h];
    float a = amp[o * NH + h];
    w_t[h * OUT_F + o] = a * cosf(p);
}

// ---------------------------------------------------------------------------
// K2: res_p[s][h][t] = sum_{i in K-quarter s} x[t][i] * basis[h][i]
// R5 structure, but K-chunk 128 -> 64: LDS 50.7 -> 26.1 KB, so the whole
// 1024-block grid is resident at once (4 blocks/CU = 4 waves/SIMD, no tail
// round; R5 was 3 blocks/CU + a tail dispatch). Chip-wide instruction totals
// and per-thread accumulation order identical to R5 -> bitwise-same result.
// ---------------------------------------------------------------------------
#define G1_TT 64
#define G1_KC 64
#define G1_S  68
#define KSPL  4
#define KQ    (IN_F / KSPL)   // 256

__global__ __launch_bounds__(256, 4) void resonance_kernel(
    const float* __restrict__ x,      // [16384][1024]
    const float* __restrict__ basis,  // [32][1024]
    float* __restrict__ res_p)        // [4][32][16384]
{
    __shared__ float xs[G1_TT * G1_S];   // 17.4 KB
    __shared__ float bs[NH * G1_S];      // 8.7 KB

    const int tid = threadIdx.x;
    const int t0  = blockIdx.x * G1_TT;
    const int ks  = blockIdx.y;              // K-quarter 0..3
    const int kb  = ks * KQ;
    const int ty  = tid >> 4;   // 0..15 : token group (4 tokens)
    const int tx  = tid & 15;   // h = tx, tx+16

    float acc[4][2] = {};

    for (int i0 = kb; i0 < kb + KQ; i0 += G1_KC) {
        // stage x tile: 64 rows x 64 floats = 1024 float4 / 256 thr = 4 each
        #pragma unroll
        for (int it = 0; it < 4; ++it) {
            int lin = it * 256 + tid;
            int r = lin >> 4, c = lin & 15;           // 16 float4 per row
            float4 v = *(const float4*)(x + (size_t)(t0 + r) * IN_F + i0 + 4 * c);
            *(float4*)(xs + r * G1_S + 4 * c) = v;
        }
        // stage basis tile: 32 x 64 = 512 float4 / 256 thr = 2 each
        #pragma unroll
        for (int it = 0; it < 2; ++it) {
            int lin = it * 256 + tid;
            int r = lin >> 4, c = lin & 15;
            float4 v = *(const float4*)(basis + (size_t)r * IN_F + i0 + 4 * c);
            *(float4*)(bs + r * G1_S + 4 * c) = v;
        }
        __syncthreads();

        #pragma unroll 4
        for (int i = 0; i < G1_KC; i += 4) {
            float4 xa[4], bb[2];
            #pragma unroll
            for (int k = 0; k < 4; ++k)
                xa[k] = *(const float4*)(xs + (4 * ty + k) * G1_S + i);
            #pragma unroll
            for (int j = 0; j < 2; ++j)
                bb[j] = *(const float4*)(bs + (tx + 16 * j) * G1_S + i);
            #pragma unroll
            for (int k = 0; k < 4; ++k) {
                #pragma unroll
                for (int j = 0; j < 2; ++j) {
                    acc[k][j] += xa[k].x * bb[j].x;
                    acc[k][j] += xa[k].y * bb[j].y;
                    acc[k][j] += xa[k].z * bb[j].z;
                    acc[k][j] += xa[k].w * bb[j].w;
                }
            }
        }
        __syncthreads();
    }

    #pragma unroll
    for (int k = 0; k < 4; ++k)
        #pragma unroll
        for (int j = 0; j < 2; ++j)
            res_p[(size_t)(ks * NH + tx + 16 * j) * T_TOK + t0 + 4 * ty + k] = acc[k][j];
}

// ---------------------------------------------------------------------------
// K3: out[t][o] = sum_h (sum_s res_p[s][h][t]) * w_t[h][o]
// R5-VERBATIM (R0 structure + 4-partial sum folded into rs staging).
// ---------------------------------------------------------------------------
#define G2_TT 64
#define G2_OT 128
#define RS_S  68
#define WT_S  132

__global__ __launch_bounds__(256) void holo_out_kernel(
    const float* __restrict__ res_p,  // [4][32][16384]
    const float* __restrict__ w_t,    // [32][4096]
    float* __restrict__ out)          // [16384][4096]
{
    __shared__ float rs[NH * RS_S];   // 8.7 KB
    __shared__ float wl[NH * WT_S];   // 16.9 KB

    const int tid = threadIdx.x;
    const int o0  = blockIdx.x * G2_OT;
    const int t0  = blockIdx.y * G2_TT;
    const int ty  = tid >> 4;   // 0..15 : token group (4 tokens)
    const int tx  = tid & 15;   // output cols 4*tx and 64+4*tx

    // stage res tile: 32 rows x 64 floats = 512 float4 -> 2/thread,
    // summing the 4 K-partials on the way in.
    #pragma unroll
    for (int it = 0; it < 2; ++it) {
        int lin = it * 256 + tid;                 // 0..511
        int r = lin >> 4, c = lin & 15;           // 16 float4 per row
        const float* rp = res_p + (size_t)r * T_TOK + t0 + 4 * c;
        float4 v = *(const float4*)(rp);
        #pragma unroll
        for (int s = 1; s < KSPL; ++s) {
            float4 u = *(const float4*)(rp + (size_t)s * NH * T_TOK);
            v.x += u.x; v.y += u.y; v.z += u.z; v.w += u.w;
        }
        *(float4*)(rs + r * RS_S + 4 * c) = v;
    }
    // stage w_t tile: 32 rows x 128 floats = 1024 float4 -> 4/thread
    #pragma unroll
    for (int it = 0; it < 4; ++it) {
        int lin = it * 256 + tid;
        int r = lin >> 5, c = lin & 31;
        float4 v = *(const float4*)(w_t + (size_t)r * OUT_F + o0 + 4 * c);
        *(float4*)(wl + r * WT_S + 4 * c) = v;
    }
    __syncthreads();

    float acc[4][8] = {};
    #pragma unroll
    for (int h = 0; h < NH; ++h) {
        float4 rt = *(const float4*)(rs + h * RS_S + 4 * ty);
        float4 wa = *(const float4*)(wl + h * WT_S + 4 * tx);
        float4 wb = *(const float4*)(wl + h * WT_S + 64 + 4 * tx);
        float r4[4] = {rt.x, rt.y, rt.z, rt.w};
        float w8[8] = {wa.x, wa.y, wa.z, wa.w, wb.x, wb.y, wb.z, wb.w};
        #pragma unroll
        for (int k = 0; k < 4; ++k)
            #pragma unroll
            for (int j = 0; j < 8; ++j)
                acc[k][j] += r4[k] * w8[j];
    }

    #pragma unroll
    for (int k = 0; k < 4; ++k) {
        float* po = out + (size_t)(t0 + 4 * ty + k) * OUT_F + o0;
        *(float4*)(po + 4 * tx)      = make_float4(acc[k][0], acc[k][1], acc[k][2], acc[k][3]);
        *(float4*)(po + 64 + 4 * tx) = make_float4(acc[k][4], acc[k][5], acc[k][6], acc[k][7]);
    }
}

// ---------------------------------------------------------------------------
extern "C" void kernel_launch(void* const* d_in, const int* in_sizes, int n_in,
                              void* d_out, int out_size, void* d_ws, size_t ws_size,
                              hipStream_t stream)
{
    const float* x     = (const float*)d_in[0];  // [16384,1024]
    const float* basis = (const float*)d_in[1];  // [32,1024]
    const float* phase = (const float*)d_in[2];  // [4096,32]
    const float* amp   = (const float*)d_in[3];  // [4096,32]
    float* out = (float*)d_out;                  // [16384,4096] fp32

    float* res_p = (float*)d_ws;                        // 4*32*16384 floats = 8 MB
    float* w_t   = res_p + (size_t)KSPL * NH * T_TOK;   // 32*4096 floats = 512 KB

    wreal_kernel<<<dim3((OUT_F * NH) / 256), dim3(256), 0, stream>>>(phase, amp, w_t);
    resonance_kernel<<<dim3(T_TOK / G1_TT, KSPL), dim3(256), 0, stream>>>(x, basis, res_p);
    holo_out_kernel<<<dim3(OUT_F / G2_OT, T_TOK / G2_TT), dim3(256), 0, stream>>>(res_p, w_t, out);
}